// Round 5
// baseline (267.451 us; speedup 1.0000x reference)
//
#include <hip/hip_runtime.h>

// Quantizer via bf16x3-split MFMA GEMM + exact-fp32 recheck of near-ties.
//   x: [16,64,32,32] fp32, embed: [64,8192] fp32
//   out[row][c] = embedT[argmax_j (f_row.e_j - ||e_j||^2/2)][c]
//
// R5: no LDS / no barriers in the hot loop — code fragments stream from
// global (L1/L2-resident) straight into MFMA A-operands; pixels resident in
// VGPRs as B-operands. Transposed MFMA => each acc's 4 elements = 4
// consecutive codes of ONE pixel => 6-op quad tournament + 5-op merge
// (11 VALU / 4 scores). Within-quad index resolved by 4 exact fp32 dots in
// reduce_rows; near-ties (margin < 1e-2) get a full exact rescan.

typedef __attribute__((ext_vector_type(8))) __bf16 bf16x8;
typedef __attribute__((ext_vector_type(4))) float f32x4;
typedef unsigned int u32;
typedef unsigned long long u64;

#define N_ROWS  16384
#define E_DIM   64
#define N_EMBED 8192
#define NCHUNK  8
#define COLS_PER_BLOCK (N_EMBED / NCHUNK)   // 1024
#define N_ST (COLS_PER_BLOCK / 64)          // 16
#define ROWS_PER_BLOCK 128                  // 4 waves x 32 pixels
#define N_ROWBLK (N_ROWS / ROWS_PER_BLOCK)  // 128
#define MARGIN_THR 1e-2f

// ---- workspace byte offsets (~9.7 MB total)
#define WS_AH   0u              // pixel hi  [16384][64] bf16
#define WS_AL   (2u << 20)      // pixel lo
#define WS_BH   (4u << 20)      // code  hi  [8192][64] bf16 (128 B/code)
#define WS_BL   (5u << 20)      // code  lo
#define WS_ET   (6u << 20)      // embedT fp32 [8192][64]
#define WS_BIAS (8u << 20)      // -||e_j||^2/2
#define WS_PB1  (WS_BIAS + (64u << 10))
#define WS_PI1  (WS_PB1 + (512u << 10))
#define WS_PB2  (WS_PI1 + (512u << 10))
#define WS_FIDX (WS_PB2 + (512u << 10))
#define WS_FLAG (WS_FIDX + (64u << 10))
#define WS_CNT  (WS_FLAG + (64u << 10))

__device__ __forceinline__ u32 f32_key(float s) {
    u32 u = __float_as_uint(s);
    return (u & 0x80000000u) ? ~u : (u | 0x80000000u);
}

// ---- K1: prep. Blocks 0..255: split x -> A_hi/A_lo [row][64] bf16.
//          Blocks 256..383: transpose embed tile -> embedT fp32, B_hi/B_lo, bias.
__global__ __launch_bounds__(256) void prep(
        const float* __restrict__ x, const float* __restrict__ embed, char* ws) {
    __shared__ float tile[64][65];
    __bf16* Ah = (__bf16*)(ws + WS_AH);
    __bf16* Al = (__bf16*)(ws + WS_AL);
    __bf16* Bh = (__bf16*)(ws + WS_BH);
    __bf16* Bl = (__bf16*)(ws + WS_BL);
    float*  eT = (float*)(ws + WS_ET);
    float*  bias = (float*)(ws + WS_BIAS);
    const int t = threadIdx.x;
    const int blk = blockIdx.x;

    if (blk < 256) {
        const int b = blk >> 4, p0 = (blk & 15) * 64;
        {
            const int c = t >> 2, seg = (t & 3) * 16;
            const float* src = x + b * 65536 + c * 1024 + p0 + seg;
#pragma unroll
            for (int i = 0; i < 16; ++i) tile[c][seg + i] = src[i];
        }
        __syncthreads();
        const int p = t >> 2, cq = (t & 3) * 16;
        const long row = b * 1024 + p0 + p;
        bf16x8 vh0, vh1, vl0, vl1;
#pragma unroll
        for (int i = 0; i < 16; ++i) {
            float f = tile[cq + i][p];
            __bf16 h = (__bf16)f;
            __bf16 l = (__bf16)(f - (float)h);
            if (i < 8) { vh0[i] = h; vl0[i] = l; }
            else       { vh1[i - 8] = h; vl1[i - 8] = l; }
        }
        *(bf16x8*)(Ah + row * 64 + cq) = vh0;
        *(bf16x8*)(Ah + row * 64 + cq + 8) = vh1;
        *(bf16x8*)(Al + row * 64 + cq) = vl0;
        *(bf16x8*)(Al + row * 64 + cq + 8) = vl1;
    } else {
        if (blk == 256 && t == 0) *(int*)(ws + WS_CNT) = 0;
        const int jbase = (blk - 256) * 64;
        {
            const int c = t >> 2, seg = (t & 3) * 16;
            const float* src = embed + c * N_EMBED + jbase + seg;
#pragma unroll
            for (int i = 0; i < 16; ++i) tile[c][seg + i] = src[i];
        }
        __syncthreads();
        if (t < 64) {
            float s = 0.f;
#pragma unroll
            for (int c = 0; c < 64; ++c) { float v = tile[c][t]; s = fmaf(v, v, s); }
            bias[jbase + t] = -0.5f * s;
        }
        const int jl = t >> 2, cq = (t & 3) * 16;
        const long row = jbase + jl;
        bf16x8 vh0, vh1, vl0, vl1;
#pragma unroll
        for (int i = 0; i < 16; ++i) {
            float f = tile[cq + i][jl];
            eT[row * 64 + cq + i] = f;
            __bf16 h = (__bf16)f;
            __bf16 l = (__bf16)(f - (float)h);
            if (i < 8) { vh0[i] = h; vl0[i] = l; }
            else       { vh1[i - 8] = h; vl1[i - 8] = l; }
        }
        *(bf16x8*)(Bh + row * 64 + cq) = vh0;
        *(bf16x8*)(Bh + row * 64 + cq + 8) = vh1;
        *(bf16x8*)(Bl + row * 64 + cq) = vl0;
        *(bf16x8*)(Bl + row * 64 + cq + 8) = vl1;
    }
}

// ---- K2: MFMA GEMM + running (top-2, quad-base) argmax. 1024 blocks, 4/CU.
__global__ __launch_bounds__(256, 4) void qdist(const char* __restrict__ ws_c, char* ws) {
    const __bf16* Ah = (const __bf16*)(ws_c + WS_AH);
    const __bf16* Al = (const __bf16*)(ws_c + WS_AL);
    const char* ChB = ws_c + WS_BH;    // code hi, 128 B per code
    const char* ClB = ws_c + WS_BL;
    const float* biasg = (const float*)(ws_c + WS_BIAS);
    float* pb1 = (float*)(ws + WS_PB1);
    int*   pi1 = (int*)(ws + WS_PI1);
    float* pb2 = (float*)(ws + WS_PB2);

    const int t = threadIdx.x;
    const int wv = t >> 6, lane = t & 63, ln = lane & 15, q = lane >> 4;
    const int rb = blockIdx.x >> 3, chunk = blockIdx.x & 7;
    const int row0 = rb * ROWS_PER_BLOCK;
    const int col0 = chunk * COLS_PER_BLOCK;

    // resident pixel fragments (B-operand): 2 pixel-tiles x 2 K-halves x {hi,lo}
    bf16x8 pfh[2][2], pfl[2][2];
#pragma unroll
    for (int nt = 0; nt < 2; ++nt) {
        long row = row0 + wv * 32 + nt * 16 + ln;
        long base = row * 64 + q * 8;
        pfh[nt][0] = *(const bf16x8*)(Ah + base);
        pfh[nt][1] = *(const bf16x8*)(Ah + base + 32);
        pfl[nt][0] = *(const bf16x8*)(Al + base);
        pfl[nt][1] = *(const bf16x8*)(Al + base + 32);
    }

    float b1[2] = {-3.4e38f, -3.4e38f};
    float b2[2] = {-3.4e38f, -3.4e38f};
    int   iq[2] = {0, 0};

    const int laneoff = ln * 128 + q * 16;   // byte offset within a 16-code tile

#pragma unroll 2
    for (int st = 0; st < N_ST; ++st) {
#pragma unroll
        for (int ct = 0; ct < 4; ++ct) {
            const int cbase = col0 + st * 64 + ct * 16;   // first code of tile
            const char* ch = ChB + ((size_t)cbase << 7);
            const char* cl = ClB + ((size_t)cbase << 7);
            // code fragments (A-operand): coalesced 1KB wave loads
            bf16x8 ah0 = *(const bf16x8*)(ch + laneoff);
            bf16x8 ah1 = *(const bf16x8*)(ch + laneoff + 64);
            bf16x8 al0 = *(const bf16x8*)(cl + laneoff);
            bf16x8 al1 = *(const bf16x8*)(cl + laneoff + 64);
            f32x4 bv = *(const f32x4*)(biasg + cbase + q * 4);  // bias for 4 codes
            const int jq = cbase + q * 4;
#pragma unroll
            for (int nt = 0; nt < 2; ++nt) {
                f32x4 acc = __builtin_amdgcn_mfma_f32_16x16x32_bf16(al0, pfh[nt][0], bv, 0, 0, 0);
                acc = __builtin_amdgcn_mfma_f32_16x16x32_bf16(al1, pfh[nt][1], acc, 0, 0, 0);
                acc = __builtin_amdgcn_mfma_f32_16x16x32_bf16(ah0, pfl[nt][0], acc, 0, 0, 0);
                acc = __builtin_amdgcn_mfma_f32_16x16x32_bf16(ah1, pfl[nt][1], acc, 0, 0, 0);
                acc = __builtin_amdgcn_mfma_f32_16x16x32_bf16(ah0, pfh[nt][0], acc, 0, 0, 0);
                acc = __builtin_amdgcn_mfma_f32_16x16x32_bf16(ah1, pfh[nt][1], acc, 0, 0, 0);
                // tournament: (max, second) of the 4 codes (one pixel)
                float m01 = fmaxf(acc[0], acc[1]), n01 = fminf(acc[0], acc[1]);
                float m23 = fmaxf(acc[2], acc[3]), n23 = fminf(acc[2], acc[3]);
                float mx  = fmaxf(m01, m23);
                float s4  = fmaxf(fminf(m01, m23), fmaxf(n01, n23));
                // merge into running (b1, b2, quad-base)
                b2[nt] = fmaxf(fmaxf(fminf(b1[nt], mx), s4), b2[nt]);
                bool gt = mx > b1[nt];
                b1[nt] = fmaxf(b1[nt], mx);
                iq[nt] = gt ? jq : iq[nt];
            }
        }
    }

    // merge across the 4 quads (same pixel lives in lanes ln, ln+16, ln+32, ln+48)
#pragma unroll
    for (int m = 16; m < 64; m <<= 1) {
#pragma unroll
        for (int nt = 0; nt < 2; ++nt) {
            float o1 = __shfl_xor(b1[nt], m);
            int   oi = __shfl_xor(iq[nt], m);
            float o2 = __shfl_xor(b2[nt], m);
            b2[nt] = fmaxf(fmaxf(fminf(b1[nt], o1), o2), b2[nt]);
            bool take = (o1 > b1[nt]) || (o1 == b1[nt] && oi < iq[nt]);
            if (take) { b1[nt] = o1; iq[nt] = oi; }
        }
    }
    if (q == 0) {
#pragma unroll
        for (int nt = 0; nt < 2; ++nt) {
            int pixel = row0 + wv * 32 + nt * 16 + ln;
            int o = chunk * N_ROWS + pixel;
            pb1[o] = b1[nt];
            pi1[o] = iq[nt];
            pb2[o] = b2[nt];
        }
    }
}

// ---- K3: merge chunks per row; exact fp32 pick within winning quad;
//          flag near-ties for full exact recheck.
__global__ __launch_bounds__(256) void reduce_rows(const float* __restrict__ x, char* ws) {
    const float* pb1 = (const float*)(ws + WS_PB1);
    const int*   pi1 = (const int*)(ws + WS_PI1);
    const float* pb2 = (const float*)(ws + WS_PB2);
    const float* eT = (const float*)(ws + WS_ET);
    const float* bias = (const float*)(ws + WS_BIAS);
    int* fidx = (int*)(ws + WS_FIDX);
    int* flags = (int*)(ws + WS_FLAG);
    int* cnt = (int*)(ws + WS_CNT);
    const int row = blockIdx.x * 256 + threadIdx.x;

    float b1 = pb1[row]; int iq = pi1[row]; float b2 = pb2[row];
#pragma unroll
    for (int ch = 1; ch < NCHUNK; ++ch) {
        float o1 = pb1[ch * N_ROWS + row];
        int   oi = pi1[ch * N_ROWS + row];
        float o2 = pb2[ch * N_ROWS + row];
        b2 = fmaxf(fmaxf(fminf(b1, o1), o2), b2);
        if (o1 > b1 || (o1 == b1 && oi < iq)) { b1 = o1; iq = oi; }
    }

    if (b1 - b2 < MARGIN_THR) {
        fidx[row] = iq;                       // placeholder; recheck overwrites
        flags[atomicAdd(cnt, 1)] = row;
    } else {
        // exact fp32 argmax within the winning quad (codes iq..iq+3)
        float xr[64];
        const float* xb = x + (row >> 10) * 65536 + (row & 1023);
#pragma unroll
        for (int c = 0; c < 64; ++c) xr[c] = xb[c * 1024];
        float best = -3.4e38f; int bi = iq;
#pragma unroll
        for (int cc = 0; cc < 4; ++cc) {
            const int j = iq + cc;
            const float* e = eT + j * 64;
            float s = bias[j];
#pragma unroll
            for (int c = 0; c < 64; ++c) s = fmaf(xr[c], e[c], s);
            if (s > best) { best = s; bi = j; }   // strict >, ascending j
        }
        fidx[row] = bi;
    }
}

// ---- K4: exact fp32 rescan of flagged rows
__global__ __launch_bounds__(256) void recheck(const float* __restrict__ x, char* ws) {
    __shared__ float fl[64];
    __shared__ u64 red[256];
    const float* eT = (const float*)(ws + WS_ET);
    const float* bias = (const float*)(ws + WS_BIAS);
    const int* flags = (const int*)(ws + WS_FLAG);
    const int n = *(const int*)(ws + WS_CNT);
    int* fidx = (int*)(ws + WS_FIDX);
    const int t = threadIdx.x;
    for (int fi = blockIdx.x; fi < n; fi += gridDim.x) {
        const int row = flags[fi];
        __syncthreads();
        if (t < 64) fl[t] = x[(row >> 10) * 65536 + t * 1024 + (row & 1023)];
        __syncthreads();
        float lb = -3.4e38f; int li = 0;
        for (int j = t; j < N_EMBED; j += 256) {
            const float* e = eT + j * 64;
            float s = bias[j];
#pragma unroll
            for (int c = 0; c < 64; ++c) s = fmaf(fl[c], e[c], s);
            if (s > lb) { lb = s; li = j; }
        }
        red[t] = ((u64)f32_key(lb) << 32) | (u32)(~(u32)li);
        __syncthreads();
        for (int off = 128; off; off >>= 1) {
            if (t < off) { u64 o = red[t + off]; if (o > red[t]) red[t] = o; }
            __syncthreads();
        }
        if (t == 0) fidx[row] = (int)(~(u32)red[0]);
    }
}

// ---- K5: gather winning codes (exact fp32 from embedT)
__global__ __launch_bounds__(256) void gather_out(const char* __restrict__ ws,
                                                  float* __restrict__ out) {
    const int* fidx = (const int*)(ws + WS_FIDX);
    const float* eT = (const float*)(ws + WS_ET);
    int g = blockIdx.x * 256 + threadIdx.x;
    int row = g >> 6, c = g & 63;
    out[g] = eT[fidx[row] * 64 + c];
}

extern "C" void kernel_launch(void* const* d_in, const int* in_sizes, int n_in,
                              void* d_out, int out_size, void* d_ws, size_t ws_size,
                              hipStream_t stream) {
    const float* x     = (const float*)d_in[0];
    const float* embed = (const float*)d_in[1];
    float* out = (float*)d_out;
    char* ws = (char*)d_ws;

    prep<<<384, 256, 0, stream>>>(x, embed, ws);
    qdist<<<N_ROWBLK * NCHUNK, 256, 0, stream>>>(ws, ws);
    reduce_rows<<<N_ROWS / 256, 256, 0, stream>>>(x, ws);
    recheck<<<128, 256, 0, stream>>>(x, ws);
    gather_out<<<(N_ROWS * 64) / 256, 256, 0, stream>>>(ws, out);
}